// Round 14
// baseline (195.972 us; speedup 1.0000x reference)
//
#include <hip/hip_runtime.h>
#include <hip/hip_bf16.h>

#define NATOM 128
#define NB    127
#define D0    25
#define D1    50
#define D2    100
#define H1STR 72     // halves; 144 B rows, 16B-aligned
#define MROWS 176    // worst case: sum 16*ceil(c_t/16) = 176 rows (11 tiles)
#define ESTR  178    // fp32 plane stride
#define W1H_HALVES (16 * 50 * 32)     // 25600  (K 25 -> 32, zero-padded)
#define W2H_HALVES (16 * 100 * 64)    // 102400 (K 50 -> 64, zero-padded)

typedef _Float16 half8 __attribute__((ext_vector_type(8)));  // 8 fp16 = 4 VGPRs
typedef __attribute__((ext_vector_type(4))) float f32x4;

// tanh(x) = 1 - 2/(exp(2x)+1); exact at +-inf, ~1e-6 rel err.
__device__ __forceinline__ float fast_tanh(float x) {
    float e = __expf(2.0f * x);
    return 1.0f - 2.0f * __builtin_amdgcn_rcpf(e + 1.0f);
}

// ---- one-shot (per launch) fp32 -> fp16 weight repack into d_ws ----------
// W1h[idx][o][k32] (k 25..31 = 0), W2h[idx][o][k64] (k 50..63 = 0).
__global__ void cvt_kernel(const float* __restrict__ W1,
                           const float* __restrict__ W2,
                           unsigned int* __restrict__ ws) {
    const int i = blockIdx.x * 256 + threadIdx.x;   // dword index
    if (i >= (W1H_HALVES + W2H_HALVES) / 2) return;
    float v0, v1;
    if (i < W1H_HALVES / 2) {
        const int s = 2 * i;
        const int row = s >> 5, kk = s & 31;        // row = idx*50 + o
        const float* base = W1 + row * D0;
        v0 = (kk < D0) ? base[kk] : 0.f;
        v1 = (kk + 1 < D0) ? base[kk + 1] : 0.f;
    } else {
        const int s = 2 * i - W1H_HALVES;
        const int row = s >> 6, kk = s & 63;        // row = idx*100 + o
        const float* base = W2 + row * D1;
        v0 = (kk < D1) ? base[kk] : 0.f;
        v1 = (kk + 1 < D1) ? base[kk + 1] : 0.f;
    }
    union { _Float16 h[2]; unsigned int u; } cv;
    cv.h[0] = (_Float16)v0;                         // RNE, range-safe (|W|<0.21)
    cv.h[1] = (_Float16)v1;
    ws[i] = cv.u;
}

__global__ __launch_bounds__(256, 1) void feat_kernel(
    const float* __restrict__ coords,
    const int*   __restrict__ types,
    const float* __restrict__ W0, const float* __restrict__ B0,
    const float* __restrict__ B1, const float* __restrict__ B2,
    const _Float16* __restrict__ W1h, const _Float16* __restrict__ W2h,
    float* __restrict__ out)
{
    // 25344 + 11264 + 2136 + 400 + 800 + 32 = 39976 B -> 4 blocks/CU, 16 waves
    __shared__ __attribute__((aligned(16))) _Float16 H1f[MROWS][H1STR];
    // H0 planes' last read is before the 2a->2b barrier; Ms's first write is
    // after -> lifetimes disjoint. H0 split in two 16-half planes: row stride
    // 16 halves (8 dw) -> A-frag bank aliasing 4-way (was 8-way at stride 32).
    __shared__ union __attribute__((aligned(16))) {
        struct { _Float16 A[MROWS][16]; _Float16 Bb[MROWS][16]; } h0;
        float Ms[3][112];
    } u;
    __shared__ float Ep[3][ESTR];       // env_a planes; zero on pad rows = mask
    __shared__ _Float16 PB1[4][D1];     // fp16 biases (rounding <= 2e-4)
    __shared__ _Float16 PB2[4][D2];
    __shared__ int cnt[2][4];           // per-wave type counts (waves 0,1)

    const int bn = blockIdx.x;    // b*128 + n
    const int b  = bn >> 7;
    const int n  = bn & 127;
    const int k  = threadIdx.x;   // 0..255
    const int wv = k >> 6;        // wave 0..3
    const int lq = (k >> 4) & 3;  // quad within wave
    const int ln = k & 15;
    const int lane = k & 63;
    const int tn  = types[n];

    const _Float16* h0base = &u.h0.A[0][0];   // Bb = h0base + MROWS*16

    // ---- zero LDS (pad rows/cols feed MFMA -> must be 0, never NaN).
    // H1f: only cols 48..63 need zeroing (cols 0..49 of every row that 2b
    // reads are rewritten by 2a; pad rows are Ep=0-masked and 2a writes them
    // finite values). H0 planes: full zero (pad rows feed 2a's MFMA).
    {
        const uint2 z2 = {0u, 0u};
        for (int i = k; i < MROWS * 4; i += 256) {
            const int row = i >> 2;
            ((uint2*)&H1f[row][48])[i & 3] = z2;
        }
        uint2* p0 = (uint2*)h0base;
        for (int i = k; i < (MROWS * 32) / 4; i += 256) p0[i] = z2;
        float* ez = &Ep[0][0];
        for (int i = k; i < 3 * ESTR; i += 256) ez[i] = 0.f;
    }
    // ---- stage fp16 bias tables for this center type (coalesced, once)
    for (int i = k; i < 600; i += 256) {
        if (i < 200) PB1[0][i] = (_Float16)B1[tn * 200 + i];          // flat
        else         PB2[0][i - 200] = (_Float16)B2[tn * 400 + (i - 200)];
    }

    // ---- ballot-based type counts + stable ranks (pairs live in waves 0,1)
    int tj = -1, j0 = 0;
    if (k < NB) { j0 = k + (k >= n ? 1 : 0); tj = types[j0]; }   // skip self
    const unsigned long long bm0 = __ballot(tj == 0);
    const unsigned long long bm1 = __ballot(tj == 1);
    const unsigned long long bm2 = __ballot(tj == 2);
    const unsigned long long bm3 = __ballot(tj == 3);
    if (lane == 0 && wv < 2) {
        cnt[wv][0] = __popcll(bm0); cnt[wv][1] = __popcll(bm1);
        cnt[wv][2] = __popcll(bm2); cnt[wv][3] = __popcll(bm3);
    }
    int sameBefore = 0;
    if (k < NB) {
        const unsigned long long mym =
            (tj == 0) ? bm0 : (tj == 1) ? bm1 : (tj == 2) ? bm2 : bm3;
        sameBefore = __popcll(mym & ((1ULL << lane) - 1ULL));
    }
    __syncthreads();

    const int c0 = cnt[0][0] + cnt[1][0];
    const int c1 = cnt[0][1] + cnt[1][1];
    const int c2 = cnt[0][2] + cnt[1][2];
    const int c3 = cnt[0][3] + cnt[1][3];
    const int ps1 = (c0 + 15) & ~15;
    const int ps2 = ps1 + ((c1 + 15) & ~15);
    const int ps3 = ps2 + ((c2 + 15) & ~15);

    // ======== phase 1: geometry + layer 0 (thread k -> its own padded row) ==
    if (k < NB) {
        const int idx = (tn << 2) | tj;
        const int pst = (tj == 0) ? 0 : (tj == 1) ? ps1 : (tj == 2) ? ps2 : ps3;
        const int pr  = pst + sameBefore + ((wv == 1) ? cnt[0][tj] : 0);

        const float cx = coords[(b * NATOM + n) * 3 + 0];
        const float cy = coords[(b * NATOM + n) * 3 + 1];
        const float cz = coords[(b * NATOM + n) * 3 + 2];
        const float dx = cx - coords[(b * NATOM + j0) * 3 + 0];
        const float dy = cy - coords[(b * NATOM + j0) * 3 + 1];
        const float dz = cz - coords[(b * NATOM + j0) * 3 + 2];
        const float d2   = dx * dx + dy * dy + dz * dz;
        const float inv  = rsqrtf(d2);         // 1/d (= env_r)
        const float inv2 = inv * inv;
        Ep[0][pr] = dx * inv2;                 // stride-1 across lanes
        Ep[1][pr] = dy * inv2;
        Ep[2][pr] = dz * inv2;

        // layer 0: 1 -> 25 (global reads, <=4-way divergent, L1-hot)
        const float* w  = W0 + idx * D0;
        const float* bb = B0 + idx * D0;
        float h0[D0];
        #pragma unroll
        for (int o = 0; o < D0; ++o)
            h0[o] = fast_tanh(w[o] * inv + bb[o]);

        // store h0 fp16: cols 0..15 -> plane A, 16..24 -> plane Bb
        unsigned int* dA = (unsigned int*)&u.h0.A[pr][0];
        unsigned int* dB = (unsigned int*)&u.h0.Bb[pr][0];
        #pragma unroll
        for (int o = 0; o < 16; o += 2) {
            union { _Float16 h[2]; unsigned int v; } cv;
            cv.h[0] = (_Float16)h0[o];
            cv.h[1] = (_Float16)h0[o + 1];
            dA[o >> 1] = cv.v;
        }
        #pragma unroll
        for (int o = 16; o < 24; o += 2) {
            union { _Float16 h[2]; unsigned int v; } cv;
            cv.h[0] = (_Float16)h0[o];
            cv.h[1] = (_Float16)h0[o + 1];
            dB[(o - 16) >> 1] = cv.v;
        }
        {
            union { _Float16 h[2]; unsigned int v; } cl;
            cl.h[0] = (_Float16)h0[24];
            cl.h[1] = (_Float16)0.f;
            dB[4] = cl.v;                      // dw 5..7 stay 0 (pre-zeroed)
        }
    }
    __syncthreads();

    // ======== phase 2a: layer 1 via MFMA (25 -> 50), K padded to 32 ========
    // Wave wv owns N-tile o1 = wv*16+ln. B-frags + biases preloaded for all
    // 4 types (batched vmem). A[m=ln][k=lq*8+j]: k-halves 0..15 in plane A,
    // 16..31 in plane Bb. C/D: col=ln (=o1), row=lq*4+r (=m).
    {
        const int o1   = wv * 16 + ln;         // 0..63
        const bool ov1 = (o1 < D1);
        const int o1c  = ov1 ? o1 : 0;         // clamp: pad lanes load row 0
        const int rres1 = (o1 < D0) ? o1 : o1 - D0;   // o1 % 25
        // per-lane constant offsets into the split H0 planes
        const int afoff = (lq >> 1) * (MROWS * 16) + (lq & 1) * 8;
        const int resoff = (rres1 & 15) + (rres1 >> 4) * (MROWS * 16);

        half8 bfa[4];
        float b1a[4];
        #pragma unroll
        for (int t = 0; t < 4; ++t) {          // batched: 4 vmem in flight
            const int idx = (tn << 2) | t;
            bfa[t] = *(const half8*)(W1h + (idx * 50 + o1c) * 32 + lq * 8);
            b1a[t] = ov1 ? (float)PB1[t][o1c] : 0.f;
        }
        #pragma unroll
        for (int t = 0; t < 4; ++t) {
            const int cnt_t = (t == 0) ? c0 : (t == 1) ? c1 : (t == 2) ? c2 : c3;
            if (cnt_t == 0) continue;
            const int ps  = (t == 0) ? 0 : (t == 1) ? ps1 : (t == 2) ? ps2 : ps3;
            const int mtiles = (cnt_t + 15) >> 4;
            for (int mt = 0; mt < mtiles; ++mt) {
                const int mb = ps + mt * 16;
                const half8 af = *(const half8*)(h0base + (mb + ln) * 16 + afoff);
                f32x4 d = {b1a[t], b1a[t], b1a[t], b1a[t]};    // bias = C-op
                d = __builtin_amdgcn_mfma_f32_16x16x32_f16(af, bfa[t], d, 0, 0, 0);
                if (ov1) {                      // never touch cols >= 50 of H1f
                    #pragma unroll
                    for (int r = 0; r < 4; ++r) {
                        const int m = mb + lq * 4 + r;
                        const float h1v =
                            fast_tanh(d[r]) + (float)h0base[m * 16 + resoff];
                        H1f[m][o1] = (_Float16)h1v;
                    }
                }
            }
        }
    }
    __syncthreads();
    // ---- from here on, u is Ms; H0 planes are dead

    // ======== phase 2b: layer 2 via MFMA (50 -> 100) + fused M-reduce ======
    for (int nt = wv; nt < 7; nt += 4) {
        const int o  = nt * 16 + ln;           // output neuron
        const bool ov = (o < D2);
        const int oc = ov ? o : (D2 - 1);
        const int rres = oc % D1;              // residual column
        float Mc0 = 0.f, Mc1 = 0.f, Mc2 = 0.f;

        half8 bq0[4], bq1[4];
        float b2a[4];
        #pragma unroll
        for (int t = 0; t < 4; ++t) {          // batched: 8 vmem in flight
            const int idx = (tn << 2) | t;
            const _Float16* wr = W2h + (idx * 100 + oc) * 64;
            bq0[t] = *(const half8*)(wr + lq * 8);        // k<32
            bq1[t] = *(const half8*)(wr + 32 + lq * 8);   // K-pad=0
            b2a[t] = (float)PB2[t][oc];
        }
        #pragma unroll
        for (int t = 0; t < 4; ++t) {
            const int cnt_t = (t == 0) ? c0 : (t == 1) ? c1 : (t == 2) ? c2 : c3;
            if (cnt_t == 0) continue;
            const int ps  = (t == 0) ? 0 : (t == 1) ? ps1 : (t == 2) ? ps2 : ps3;
            const int mtiles = (cnt_t + 15) >> 4;
            for (int mt = 0; mt < mtiles; ++mt) {
                const int mb = ps + mt * 16;
                const _Float16* arow = &H1f[mb + ln][0];
                const half8 af0 = *(const half8*)(arow + lq * 8);
                const half8 af1 = *(const half8*)(arow + 32 + lq * 8);
                f32x4 d = {b2a[t], b2a[t], b2a[t], b2a[t]};    // bias = C-op
                d = __builtin_amdgcn_mfma_f32_16x16x32_f16(af0, bq0[t], d, 0, 0, 0);
                d = __builtin_amdgcn_mfma_f32_16x16x32_f16(af1, bq1[t], d, 0, 0, 0);
                const int mq = mb + lq * 4;
                #pragma unroll
                for (int r = 0; r < 4; ++r) {          // C/D: row = quad*4+r
                    const int m = mq + r;
                    // Ep = 0 on pad rows masks garbage
                    const float g = fast_tanh(d[r]) + (float)H1f[m][rres];
                    Mc0 += Ep[0][m] * g;
                    Mc1 += Ep[1][m] * g;
                    Mc2 += Ep[2][m] * g;
                }
            }
        }
        // reduce across the 4 quads (rows); lanes differ only in lq
        Mc0 += __shfl_xor(Mc0, 16, 64); Mc1 += __shfl_xor(Mc1, 16, 64);
        Mc2 += __shfl_xor(Mc2, 16, 64);
        Mc0 += __shfl_xor(Mc0, 32, 64); Mc1 += __shfl_xor(Mc1, 32, 64);
        Mc2 += __shfl_xor(Mc2, 32, 64);
        if (lq == 0 && ov) {
            u.Ms[0][o] = Mc0; u.Ms[1][o] = Mc1; u.Ms[2][o] = Mc2;
        }
    }
    __syncthreads();

    // ======== phase 3: out[m][a] = sum_c M[c][m] * M[c][a], a < 4 ==========
    if (k < D2) {
        const float m0 = u.Ms[0][k], m1 = u.Ms[1][k], m2 = u.Ms[2][k];
        float4 o4;
        o4.x = m0 * u.Ms[0][0] + m1 * u.Ms[1][0] + m2 * u.Ms[2][0];
        o4.y = m0 * u.Ms[0][1] + m1 * u.Ms[1][1] + m2 * u.Ms[2][1];
        o4.z = m0 * u.Ms[0][2] + m1 * u.Ms[1][2] + m2 * u.Ms[2][2];
        o4.w = m0 * u.Ms[0][3] + m1 * u.Ms[1][3] + m2 * u.Ms[2][3];
        reinterpret_cast<float4*>(out)[bn * D2 + k] = o4;   // 16B-aligned
    }
}

extern "C" void kernel_launch(void* const* d_in, const int* in_sizes, int n_in,
                              void* d_out, int out_size, void* d_ws, size_t ws_size,
                              hipStream_t stream) {
    (void)in_sizes; (void)n_in; (void)out_size; (void)ws_size;
    const float* coords = (const float*)d_in[0];
    const int*   types  = (const int*)  d_in[1];
    const float* W0 = (const float*)d_in[2];
    const float* B0 = (const float*)d_in[3];
    const float* W1 = (const float*)d_in[4];
    const float* B1 = (const float*)d_in[5];
    const float* W2 = (const float*)d_in[6];
    const float* B2 = (const float*)d_in[7];
    float* out = (float*)d_out;

    _Float16* W1h = (_Float16*)d_ws;                 // 25600 halves
    _Float16* W2h = (_Float16*)d_ws + W1H_HALVES;    // 102400 halves

    const int cvt_dwords = (W1H_HALVES + W2H_HALVES) / 2;      // 64000
    cvt_kernel<<<(cvt_dwords + 255) / 256, 256, 0, stream>>>(
        W1, W2, (unsigned int*)d_ws);

    feat_kernel<<<64 * NATOM, 256, 0, stream>>>(
        coords, types, W0, B0, B1, B2, W1h, W2h, out);
}